// Round 3
// baseline (840.628 us; speedup 1.0000x reference)
//
#include <hip/hip_runtime.h>
#include <hip/hip_bf16.h>

// GGCN: g1=relu(A@(x@W1)+b1); g2=relu(A@(g1@W2)+b2); out=relu(g2@Wd1+bd1)@Wd2+bd2
// N=16384, F=32, H=64. A dense f32 [N][N] = 1.07 GB, read twice -> HBM-bound,
// floor ~341 us. R3 redesign: ZERO-barrier, ZERO-LDS streaming GEMM.
//  - mfma_32x32x16_bf16 operand frags loaded DIRECTLY from global:
//    A-frag: 32 contiguous B/lane (full 64-B sectors per lane pair) from HBM (nt),
//    B-frag: 16 contiguous B/lane from L2-resident Ht (2 MB).
//  - block = 256 thr = 4 independent waves, each a K-quarter (split-K);
//    register double-buffered 64-k chunks; compiler counted-vmcnt paces waves.
//  - single end-of-kernel LDS reduce + bias + relu.

typedef __bf16 bf16x8 __attribute__((ext_vector_type(8)));
typedef float  f32x16 __attribute__((ext_vector_type(16)));
typedef float  f32x4v __attribute__((ext_vector_type(4)));
typedef int    i32x4  __attribute__((ext_vector_type(4)));

#define NNODE 16384
#define KDIM  16384
#define HCOL  64

__device__ inline bf16x8 pack8(f32x4v a, f32x4v b){
  bf16x8 t;
  t[0]=(__bf16)a[0]; t[1]=(__bf16)a[1]; t[2]=(__bf16)a[2]; t[3]=(__bf16)a[3];
  t[4]=(__bf16)b[0]; t[5]=(__bf16)b[1]; t[6]=(__bf16)b[2]; t[7]=(__bf16)b[3];
  return t;
}

// ---------------- big kernel: G = relu(A @ Ht^T + bias) ----------------
__global__ __launch_bounds__(256, 2) void gcn_layer_kernel(
    const float* __restrict__ A,      // [16384][16384] f32
    const __bf16* __restrict__ Ht,    // [64][16384] bf16 (H transposed, k contiguous)
    const float* __restrict__ bias,   // [64]
    float* __restrict__ G)            // [16384][64] f32
{
  __shared__ float red[3*32*64];      // partials of waves 1..3 (24 KB)

  const int tid  = threadIdx.x;
  const int lane = tid & 63;
  const int kw   = tid >> 6;          // K-quarter 0..3
  const int row0 = blockIdx.x * 32;
  const int r    = lane & 31;         // A-row / B-col within tile
  const int hsub = lane >> 5;         // which 8-k half of the 16-k window

  const size_t k0 = (size_t)kw * 4096;
  const float*  pa  = A  + (size_t)(row0 + r) * KDIM + k0 + (size_t)hsub*8;
  const __bf16* pb0 = Ht + (size_t)r        * KDIM + k0 + (size_t)hsub*8;
  const __bf16* pb1 = Ht + (size_t)(r + 32) * KDIM + k0 + (size_t)hsub*8;

  f32x16 acc0 = {}; f32x16 acc1 = {};

  // two named register chunk-buffers (static indexing only)
  f32x4v a0[8], a1[8];
  i32x4  b00[4], b01[4], b10[4], b11[4];

  // one 64-k chunk: A 8x dwordx4 (32B/lane per 16-k step), B 2x4 dwordx4
  auto LOAD = [&](f32x4v (&a)[8], i32x4 (&b0)[4], i32x4 (&b1)[4], int t){
    const float* p = pa + (size_t)t*64;
    #pragma unroll
    for (int kk=0; kk<4; ++kk){
      a[2*kk]   = __builtin_nontemporal_load((const f32x4v*)(p + kk*16));     // A: stream
      a[2*kk+1] = __builtin_nontemporal_load((const f32x4v*)(p + kk*16 + 4));
    }
    const __bf16* q0 = pb0 + (size_t)t*64;
    const __bf16* q1 = pb1 + (size_t)t*64;
    #pragma unroll
    for (int kk=0; kk<4; ++kk){
      b0[kk] = *(const i32x4*)(q0 + kk*16);    // Ht: L2-resident, keep cached
      b1[kk] = *(const i32x4*)(q1 + kk*16);
    }
  };

  auto COMP = [&](f32x4v (&a)[8], i32x4 (&b0)[4], i32x4 (&b1)[4]){
    #pragma unroll
    for (int kk=0; kk<4; ++kk){
      bf16x8 af = pack8(a[2*kk], a[2*kk+1]);
      acc0 = __builtin_amdgcn_mfma_f32_32x32x16_bf16(af, __builtin_bit_cast(bf16x8, b0[kk]), acc0, 0,0,0);
      acc1 = __builtin_amdgcn_mfma_f32_32x32x16_bf16(af, __builtin_bit_cast(bf16x8, b1[kk]), acc1, 0,0,0);
    }
  };

  LOAD(a0, b00, b01, 0);
  LOAD(a1, b10, b11, 1);
  #pragma unroll 1
  for (int t=0; t<62; t+=2){
    COMP(a0, b00, b01);            // waits (counted vmcnt) chunk t, issued 1 iter ago
    LOAD(a0, b00, b01, t+2);       // refill immediately -> stays in flight
    COMP(a1, b10, b11);
    LOAD(a1, b10, b11, t+3);
  }
  COMP(a0, b00, b01);
  COMP(a1, b10, b11);

  // ---- split-K reduce: waves 1..3 dump partials, wave 0 combines ----
  if (kw > 0){
    float* rd = red + (kw-1)*2048;
    #pragma unroll
    for (int j=0; j<16; ++j){
      int rr = (j&3) + 8*(j>>2) + 4*hsub;     // C/D layout: col=lane&31 [verified R1]
      rd[rr*64 + r]      = acc0[j];
      rd[rr*64 + 32 + r] = acc1[j];
    }
  }
  __syncthreads();
  if (kw == 0){
    #pragma unroll
    for (int j=0; j<16; ++j){
      int rr = (j&3) + 8*(j>>2) + 4*hsub;
      float v0 = acc0[j] + red[rr*64+r]      + red[2048+rr*64+r]      + red[4096+rr*64+r]      + bias[r];
      float v1 = acc1[j] + red[rr*64+32+r]   + red[2048+rr*64+32+r]   + red[4096+rr*64+32+r]   + bias[32+r];
      G[(size_t)(row0 + rr)*HCOL + r]      = fmaxf(v0, 0.f);
      G[(size_t)(row0 + rr)*HCOL + 32 + r] = fmaxf(v1, 0.f);
    }
  }
}

// ---------------- projection: out[h][n] = sum_f in[n][f]*W[f][h], bf16 out ----------------
template<int F>
__global__ __launch_bounds__(128) void proj_T_kernel(
    const float* __restrict__ in,   // [N][F]
    const float* __restrict__ W,    // [F][64]
    __bf16* __restrict__ out)       // [64][N]
{
  constexpr int FP = F + 4;
  __shared__ float sWt[64*FP];      // W transposed [h][f], padded
  __shared__ short sOut[64*136];    // [h][128 nodes], padded

  int tid = threadIdx.x;
  for (int e = tid; e < 64*F; e += 128){
    int h = e / F, j = e - h*F;
    sWt[h*FP + j] = W[j*64 + h];
  }
  __syncthreads();

  const size_t n = (size_t)blockIdx.x*128 + tid;
  float rowv[F];
  #pragma unroll
  for (int j=0; j<F; j+=4){
    f32x4v v = *(const f32x4v*)(in + n*F + j);
    rowv[j]=v[0]; rowv[j+1]=v[1]; rowv[j+2]=v[2]; rowv[j+3]=v[3];
  }
  #pragma unroll
  for (int h=0; h<64; ++h){
    float s = 0.f;
    #pragma unroll
    for (int j=0; j<F; j+=4){
      f32x4v w = *(const f32x4v*)&sWt[h*FP + j];
      s += rowv[j]*w[0] + rowv[j+1]*w[1] + rowv[j+2]*w[2] + rowv[j+3]*w[3];
    }
    sOut[h*136 + tid] = __builtin_bit_cast(short, (__bf16)s);
  }
  __syncthreads();

  const size_t n0 = (size_t)blockIdx.x*128;
  #pragma unroll
  for (int pi=0; pi<8; ++pi){
    int p = pi*128 + tid;
    int h = p >> 4, cc = p & 15;
    i32x4 v = *(const i32x4*)&sOut[h*136 + cc*8];
    *(i32x4*)(out + (size_t)h*NNODE + n0 + cc*8) = v;
  }
}

// ---------------- tail MLP: out[n] = relu(g2[n]@Wd1+bd1)@Wd2 + bd2 ----------------
__global__ __launch_bounds__(256) void tail_kernel(
    const float* __restrict__ g2,   // [N][64]
    const float* __restrict__ Wd1,  // [64][32]
    const float* __restrict__ bd1,  // [32]
    const float* __restrict__ Wd2,  // [32][1]
    const float* __restrict__ bd2,  // [1]
    float* __restrict__ outp)       // [N]
{
  __shared__ float sW[64*32];
  __shared__ float sb1[32], sw2[32];
  int tid = threadIdx.x;
  for (int e=tid; e<2048; e+=256) sW[e] = Wd1[e];
  if (tid < 32){ sb1[tid] = bd1[tid]; sw2[tid] = Wd2[tid]; }
  __syncthreads();

  size_t n = (size_t)blockIdx.x*256 + tid;
  float rv[64];
  #pragma unroll
  for (int j=0;j<64;j+=4){
    f32x4v v = *(const f32x4v*)(g2 + n*64 + j);
    rv[j]=v[0]; rv[j+1]=v[1]; rv[j+2]=v[2]; rv[j+3]=v[3];
  }
  float o = 0.f;
  #pragma unroll
  for (int c=0;c<32;++c){
    float s = sb1[c];
    #pragma unroll
    for (int j=0;j<64;++j) s += rv[j]*sW[j*32 + c];
    o += fmaxf(s, 0.f) * sw2[c];
  }
  outp[n] = o + bd2[0];
}

extern "C" void kernel_launch(void* const* d_in, const int* in_sizes, int n_in,
                              void* d_out, int out_size, void* d_ws, size_t ws_size,
                              hipStream_t stream)
{
  const float* x   = (const float*)d_in[0];
  const float* a   = (const float*)d_in[1];
  const float* W1  = (const float*)d_in[2];
  const float* b1  = (const float*)d_in[3];
  const float* W2  = (const float*)d_in[4];
  const float* b2  = (const float*)d_in[5];
  const float* Wd1 = (const float*)d_in[6];
  const float* bd1 = (const float*)d_in[7];
  const float* Wd2 = (const float*)d_in[8];
  const float* bd2 = (const float*)d_in[9];
  float* outp = (float*)d_out;

  char* ws = (char*)d_ws;                       // needs 12 MB
  __bf16* Ht1 = (__bf16*)(ws);                  // [64][16384] bf16, 2 MB
  __bf16* Ht2 = (__bf16*)(ws + (2u<<20));       // 2 MB
  float*  g1  = (float*)(ws + (4u<<20));        // [16384][64] f32, 4 MB
  float*  g2  = (float*)(ws + (8u<<20));        // 4 MB

  proj_T_kernel<32><<<128, 128, 0, stream>>>(x,  W1, Ht1);
  gcn_layer_kernel <<<512, 256, 0, stream>>>(a, Ht1, b1, g1);
  proj_T_kernel<64><<<128, 128, 0, stream>>>(g1, W2, Ht2);
  gcn_layer_kernel <<<512, 256, 0, stream>>>(a, Ht2, b2, g2);
  tail_kernel      <<<64, 256, 0, stream>>>(g2, Wd1, bd1, Wd2, bd2, outp);
}

// Round 4
// 573.231 us; speedup vs baseline: 1.4665x; 1.4665x over previous
//
#include <hip/hip_runtime.h>
#include <hip/hip_bf16.h>

// GGCN: g1=relu(A@(x@W1)+b1); g2=relu(A@(g1@W2)+b2); out=relu(g2@Wd1+bd1)@Wd2+bd2
// N=16384, F=32, H=64. A dense f32 = 1.07 GB read twice -> HBM floor ~341 us.
// R4: barrier-free streaming GEMM. 1-wave blocks, split-K=4 (2048 blocks = 8
// waves/CU, 4x R1 occupancy). A staged f32 via fully-contiguous 1KB/instr loads
// -> wave-private dbuf LDS (XOR swizzle), cvt to bf16 at compute. B frags direct
// from L2-resident Ht. Split-K partials in ws + small reduce kernel.

typedef __bf16 bf16x8 __attribute__((ext_vector_type(8)));
typedef float  f32x16 __attribute__((ext_vector_type(16)));
typedef float  f32x4v __attribute__((ext_vector_type(4)));
typedef int    i32x4  __attribute__((ext_vector_type(4)));

#define NNODE 16384
#define KDIM  16384
#define HCOL  64

__device__ inline bf16x8 pack8(f32x4v a, f32x4v b){
  bf16x8 t;
  t[0]=(__bf16)a[0]; t[1]=(__bf16)a[1]; t[2]=(__bf16)a[2]; t[3]=(__bf16)a[3];
  t[4]=(__bf16)b[0]; t[5]=(__bf16)b[1]; t[6]=(__bf16)b[2]; t[7]=(__bf16)b[3];
  return t;
}

// ---------------- big kernel: gP[kq] = A[:, kq-quarter] @ Ht^T ----------------
// block = 64 threads = 1 wave. bid = rowBlk*4 + kq. No barriers at all.
__global__ __launch_bounds__(64, 2) void gcn_stream_kernel(
    const float* __restrict__ A,      // [16384][16384] f32
    const __bf16* __restrict__ Ht,    // [64][16384] bf16 (H transposed)
    float* __restrict__ gP)           // [4][16384][64] f32 partials
{
  __shared__ f32x4v sA[2][32][16];    // 2 bufs x 32 rows x 16 chunks(16B) = 16 KB

  const int lane = threadIdx.x;       // 0..63
  const int bid  = blockIdx.x;
  const int kq   = bid & 3;           // K-quarter (low bits -> per-XCD Ht locality)
  const int row0 = (bid >> 2) * 32;
  const int r    = lane & 31;
  const int hsub = lane >> 5;
  const int x7   = r & 7;

  const size_t k0 = (size_t)kq * 4096;

  // staging: instr pi reads rows pi*4+srow, lane covers 16B chunk scol of the
  // row's 256-B span -> each instruction = 4 x 256 B fully-contiguous runs.
  const int srow = lane >> 4;         // 0..3
  const int scol = lane & 15;         // 0..15
  const float* pa = A + (size_t)(row0 + srow) * KDIM + k0 + (size_t)scol * 4;

  const __bf16* pb0 = Ht + (size_t)r * KDIM + k0 + (size_t)hsub * 8;
  const __bf16* pb1 = pb0 + (size_t)32 * KDIM;

  f32x4v ra[8];
  i32x4  b0a[4], b1a[4], b0b[4], b1b[4];
  f32x16 acc0 = {}, acc1 = {};

  auto LOADA = [&](int t){
    const float* p = pa + (size_t)t * 64;
    #pragma unroll
    for (int pi = 0; pi < 8; ++pi)
      ra[pi] = *(const f32x4v*)(p + (size_t)(pi * 4) * KDIM);
  };
  auto WRITEA = [&](int buf){
    #pragma unroll
    for (int pi = 0; pi < 8; ++pi){
      int row = pi * 4 + srow;
      sA[buf][row][scol ^ (row & 7)] = ra[pi];   // XOR chunk swizzle
    }
  };
  auto LOADB = [&](i32x4 (&b0)[4], i32x4 (&b1)[4], int t){
    const __bf16* q0 = pb0 + (size_t)t * 64;
    const __bf16* q1 = pb1 + (size_t)t * 64;
    #pragma unroll
    for (int kk = 0; kk < 4; ++kk){
      b0[kk] = *(const i32x4*)(q0 + kk * 16);    // L2-resident
      b1[kk] = *(const i32x4*)(q1 + kk * 16);
    }
  };
  auto COMP = [&](int buf, i32x4 (&b0)[4], i32x4 (&b1)[4]){
    #pragma unroll
    for (int kk = 0; kk < 4; ++kk){
      int c0 = kk * 4 + hsub * 2;                // logical 16B chunk
      f32x4v lo = sA[buf][r][(c0    ) ^ x7];
      f32x4v hi = sA[buf][r][(c0 + 1) ^ x7];
      bf16x8 af = pack8(lo, hi);
      acc0 = __builtin_amdgcn_mfma_f32_32x32x16_bf16(af, __builtin_bit_cast(bf16x8, b0[kk]), acc0, 0,0,0);
      acc1 = __builtin_amdgcn_mfma_f32_32x32x16_bf16(af, __builtin_bit_cast(bf16x8, b1[kk]), acc1, 0,0,0);
    }
  };

  // 64 chunks of 64 k. Prologue: buf0 <- chunk0; ra/bB <- chunk1.
  LOADA(0); LOADB(b0a, b1a, 0);
  WRITEA(0);
  LOADA(1); LOADB(b0b, b1b, 1);

  #pragma unroll 1
  for (int t = 0; t < 64; t += 2){
    WRITEA(1);                        // chunk t+1 (ra)
    COMP(0, b0a, b1a);                // chunk t
    if (t + 2 < 64){
      LOADA(t + 2); LOADB(b0a, b1a, t + 2);
      WRITEA(0);                      // chunk t+2
    }
    COMP(1, b0b, b1b);                // chunk t+1
    if (t + 3 < 64){
      LOADA(t + 3); LOADB(b0b, b1b, t + 3);
    }
  }

  // epilogue: store this K-quarter's partial (no reduction here)
  float* out = gP + ((size_t)kq * NNODE + row0) * HCOL;
  #pragma unroll
  for (int j = 0; j < 16; ++j){
    int rr = (j & 3) + 8 * (j >> 2) + 4 * hsub;  // C/D layout [verified R1/R3]
    out[(size_t)rr * HCOL + r]      = acc0[j];
    out[(size_t)rr * HCOL + 32 + r] = acc1[j];
  }
}

// ---------------- reduce: g = relu(sum_4 partials + bias) ----------------
__global__ __launch_bounds__(256) void reduce_kernel(
    const float* __restrict__ gP,    // [4][16384][64]
    const float* __restrict__ bias,  // [64]
    float* __restrict__ g)           // [16384][64]
{
  const size_t i = (size_t)blockIdx.x * 256 + threadIdx.x;   // f32x4 index
  const f32x4v* p = (const f32x4v*)gP;
  f32x4v s = p[i];
  s += p[i +  262144];
  s += p[i +  524288];
  s += p[i +  786432];
  f32x4v b = *(const f32x4v*)(bias + (i & 15) * 4);
  f32x4v o;
  o[0] = fmaxf(s[0] + b[0], 0.f);
  o[1] = fmaxf(s[1] + b[1], 0.f);
  o[2] = fmaxf(s[2] + b[2], 0.f);
  o[3] = fmaxf(s[3] + b[3], 0.f);
  ((f32x4v*)g)[i] = o;
}

// ---------------- projection: out[h][n] = sum_f in[n][f]*W[f][h], bf16 out ----------------
template<int F>
__global__ __launch_bounds__(128) void proj_T_kernel(
    const float* __restrict__ in,   // [N][F]
    const float* __restrict__ W,    // [F][64]
    __bf16* __restrict__ out)       // [64][N]
{
  constexpr int FP = F + 4;
  __shared__ float sWt[64*FP];
  __shared__ short sOut[64*136];

  int tid = threadIdx.x;
  for (int e = tid; e < 64*F; e += 128){
    int h = e / F, j = e - h*F;
    sWt[h*FP + j] = W[j*64 + h];
  }
  __syncthreads();

  const size_t n = (size_t)blockIdx.x*128 + tid;
  float rowv[F];
  #pragma unroll
  for (int j=0; j<F; j+=4){
    f32x4v v = *(const f32x4v*)(in + n*F + j);
    rowv[j]=v[0]; rowv[j+1]=v[1]; rowv[j+2]=v[2]; rowv[j+3]=v[3];
  }
  #pragma unroll
  for (int h=0; h<64; ++h){
    float s = 0.f;
    #pragma unroll
    for (int j=0; j<F; j+=4){
      f32x4v w = *(const f32x4v*)&sWt[h*FP + j];
      s += rowv[j]*w[0] + rowv[j+1]*w[1] + rowv[j+2]*w[2] + rowv[j+3]*w[3];
    }
    sOut[h*136 + tid] = __builtin_bit_cast(short, (__bf16)s);
  }
  __syncthreads();

  const size_t n0 = (size_t)blockIdx.x*128;
  #pragma unroll
  for (int pi=0; pi<8; ++pi){
    int p = pi*128 + tid;
    int h = p >> 4, cc = p & 15;
    i32x4 v = *(const i32x4*)&sOut[h*136 + cc*8];
    *(i32x4*)(out + (size_t)h*NNODE + n0 + cc*8) = v;
  }
}

// ---------------- tail MLP: out[n] = relu(g2[n]@Wd1+bd1)@Wd2 + bd2 ----------------
__global__ __launch_bounds__(256) void tail_kernel(
    const float* __restrict__ g2,
    const float* __restrict__ Wd1,
    const float* __restrict__ bd1,
    const float* __restrict__ Wd2,
    const float* __restrict__ bd2,
    float* __restrict__ outp)
{
  __shared__ float sW[64*32];
  __shared__ float sb1[32], sw2[32];
  int tid = threadIdx.x;
  for (int e=tid; e<2048; e+=256) sW[e] = Wd1[e];
  if (tid < 32){ sb1[tid] = bd1[tid]; sw2[tid] = Wd2[tid]; }
  __syncthreads();

  size_t n = (size_t)blockIdx.x*256 + tid;
  float rv[64];
  #pragma unroll
  for (int j=0;j<64;j+=4){
    f32x4v v = *(const f32x4v*)(g2 + n*64 + j);
    rv[j]=v[0]; rv[j+1]=v[1]; rv[j+2]=v[2]; rv[j+3]=v[3];
  }
  float o = 0.f;
  #pragma unroll
  for (int c=0;c<32;++c){
    float s = sb1[c];
    #pragma unroll
    for (int j=0;j<64;++j) s += rv[j]*sW[j*32 + c];
    o += fmaxf(s, 0.f) * sw2[c];
  }
  outp[n] = o + bd2[0];
}

extern "C" void kernel_launch(void* const* d_in, const int* in_sizes, int n_in,
                              void* d_out, int out_size, void* d_ws, size_t ws_size,
                              hipStream_t stream)
{
  const float* x   = (const float*)d_in[0];
  const float* a   = (const float*)d_in[1];
  const float* W1  = (const float*)d_in[2];
  const float* b1  = (const float*)d_in[3];
  const float* W2  = (const float*)d_in[4];
  const float* b2  = (const float*)d_in[5];
  const float* Wd1 = (const float*)d_in[6];
  const float* bd1 = (const float*)d_in[7];
  const float* Wd2 = (const float*)d_in[8];
  const float* bd2 = (const float*)d_in[9];
  float* outp = (float*)d_out;

  char* ws = (char*)d_ws;                       // needs 28 MB
  __bf16* Ht1 = (__bf16*)(ws);                  // [64][16384] bf16, 2 MB
  __bf16* Ht2 = (__bf16*)(ws + (2u<<20));       // 2 MB
  float*  g1  = (float*)(ws + (4u<<20));        // [16384][64] f32, 4 MB
  float*  g2  = (float*)(ws + (8u<<20));        // 4 MB
  float*  gP  = (float*)(ws + (12u<<20));       // [4][16384][64] f32, 16 MB

  proj_T_kernel<32> <<<128, 128, 0, stream>>>(x,  W1, Ht1);
  gcn_stream_kernel <<<2048, 64, 0, stream>>>(a, Ht1, gP);
  reduce_kernel     <<<1024, 256, 0, stream>>>(gP, b1, g1);
  proj_T_kernel<64> <<<128, 128, 0, stream>>>(g1, W2, Ht2);
  gcn_stream_kernel <<<2048, 64, 0, stream>>>(a, Ht2, gP);
  reduce_kernel     <<<1024, 256, 0, stream>>>(gP, b2, g2);
  tail_kernel       <<<64, 256, 0, stream>>>(g2, Wd1, bd1, Wd2, bd2, outp);
}

// Round 5
// 509.384 us; speedup vs baseline: 1.6503x; 1.1253x over previous
//
#include <hip/hip_runtime.h>
#include <hip/hip_bf16.h>

// GGCN: g1=relu(A@(x@W1)+b1); g2=relu(A@(g1@W2)+b2); out=relu(g2@Wd1+bd1)@Wd2+bd2
// N=16384, F=32, H=64, A dense f32 [N][N] (1.07 GB, read twice -> HBM-bound).
// R5 = R1 (best, 506us) with the two main-loop __syncthreads() REMOVED.
// LDS tiles are wave-private (indexed by kw), so barriers were only pacing:
// they forced a vmcnt(0)+lgkmcnt(0) drain twice per tile. Waves now free-run.
// Single barrier kept before the split-K epilogue (red aliases wave0's sA).

typedef __bf16 bf16x8 __attribute__((ext_vector_type(8)));
typedef float  f32x16 __attribute__((ext_vector_type(16)));
typedef float  f32x4v __attribute__((ext_vector_type(4)));
typedef int    i32x4  __attribute__((ext_vector_type(4)));

#define NNODE 16384
#define KDIM  16384
#define HCOL  64

__device__ inline i32x4 pack8(f32x4v a, f32x4v b){
  bf16x8 t;
  t[0]=(__bf16)a[0]; t[1]=(__bf16)a[1]; t[2]=(__bf16)a[2]; t[3]=(__bf16)a[3];
  t[4]=(__bf16)b[0]; t[5]=(__bf16)b[1]; t[6]=(__bf16)b[2]; t[7]=(__bf16)b[3];
  return __builtin_bit_cast(i32x4, t);
}

// ---------------- big kernel: G = relu(A @ Ht^T + bias) ----------------
// block = 128 threads (2 waves). BM=32 rows. wave kw handles K-half kw.
// LDS per (kw,buf): A-tile 32x64 bf16 (4KB), H-tile 64x64 bf16 (8KB). dbuf.
// XOR swizzle on 16B chunks: physical chunk = c ^ (row&7). NO main-loop barriers.
__global__ __launch_bounds__(128) void gcn_layer_kernel(
    const float* __restrict__ A,      // [16384][16384] f32
    const __bf16* __restrict__ Ht,    // [64][16384] bf16 (transposed H)
    const float* __restrict__ bias,   // [64]
    float* __restrict__ G)            // [16384][64] f32
{
  __shared__ i32x4 sA[2*2*256];   // (kw,buf) x 32 rows x 8 chunks  (wave-private by kw)
  __shared__ i32x4 sH[2*2*512];   // (kw,buf) x 64 rows x 8 chunks  (wave-private by kw)

  const int tid  = threadIdx.x;
  const int lane = tid & 63;
  const int kw   = tid >> 6;          // K-half
  const int row0 = blockIdx.x * 32;

  const int rA0  = lane >> 3;         // 0..7 (staging row-in-group)
  const int ccA  = lane & 7;          // staging logical chunk
  const int swzA = ccA ^ rA0;         // swizzled chunk (rA0 < 8)
  const int r    = lane & 31;
  const int hsub = lane >> 5;         // 0/1 k-subgroup
  const int xs   = lane & 7;          // = r&7

  const size_t k0base = (size_t)kw * 8192;

  f32x4v ra[8]; i32x4 rh[8];

  const float* pA0 = A + (size_t)(row0 + rA0) * KDIM + k0base + (size_t)ccA*8;
  const i32x4* pH0 = (const i32x4*)Ht + (size_t)rA0 * (KDIM/8) + k0base/8 + ccA;

  auto stage_load = [&](int t){
    const float* pA = pA0 + (size_t)t*64;
    #pragma unroll
    for (int pi=0; pi<4; ++pi){
      const float* p = pA + (size_t)pi*8*KDIM;
      ra[2*pi]   = __builtin_nontemporal_load((const f32x4v*)p);       // A: streaming
      ra[2*pi+1] = __builtin_nontemporal_load((const f32x4v*)(p+4));
    }
    const i32x4* pH = pH0 + (size_t)t*8;
    #pragma unroll
    for (int pi=0; pi<8; ++pi)
      rh[pi] = pH[(size_t)pi*8*(KDIM/8)];                              // Ht: keep cached (L2)
  };

  auto stage_write = [&](int buf){
    i32x4* dA = &sA[(kw*2+buf)*256];
    #pragma unroll
    for (int pi=0; pi<4; ++pi)
      dA[(rA0 + pi*8)*8 + swzA] = pack8(ra[2*pi], ra[2*pi+1]);
    i32x4* dH = &sH[(kw*2+buf)*512];
    #pragma unroll
    for (int pi=0; pi<8; ++pi)
      dH[(rA0 + pi*8)*8 + swzA] = rh[pi];
  };

  f32x16 acc0 = {}; f32x16 acc1 = {};

  auto compute = [&](int buf){
    const i32x4* bA = &sA[(kw*2+buf)*256];
    const i32x4* bH = &sH[(kw*2+buf)*512];
    #pragma unroll
    for (int kk=0; kk<4; ++kk){
      int c = (kk*2 + hsub) ^ xs;
      bf16x8 a  = __builtin_bit_cast(bf16x8, bA[r*8 + c]);
      bf16x8 b0 = __builtin_bit_cast(bf16x8, bH[r*8 + c]);
      bf16x8 b1 = __builtin_bit_cast(bf16x8, bH[(r+32)*8 + c]);
      acc0 = __builtin_amdgcn_mfma_f32_32x32x16_bf16(a, b0, acc0, 0,0,0);
      acc1 = __builtin_amdgcn_mfma_f32_32x32x16_bf16(a, b1, acc1, 0,0,0);
    }
  };

  // prologue: buf0 <- tile0 ; regs <- tile1
  stage_load(0);
  stage_write(0);
  stage_load(1);

  // barrier-free main loop: compute(t) ; write(t+1) ; load(t+2)
  // (write-before-load preserves WAR on the single ra/rh register set;
  //  wave-private LDS dbuf needs no cross-wave sync)
  #pragma unroll 1
  for (int t=0; t<127; ++t){
    int nx = t+2; if (nx > 127) nx = 127;   // tail: redundant re-load, cache-hit
    compute(t&1);
    stage_write((t+1)&1);
    stage_load(nx);
  }
  compute(1);                 // tile 127 lives in buf 1

  __syncthreads();            // ONE barrier: red aliases wave0's sA region

  // split-K reduce (wave kw=1 -> LDS), then bias+relu+store by wave kw=0
  float* red = (float*)sA;    // reuse: 32*64 f32 = 8KB
  if (kw == 1){
    #pragma unroll
    for (int j=0; j<16; ++j){
      int rr = (j&3) + 8*(j>>2) + 4*hsub;   // C/D layout [verified R1..R4]
      red[rr*64 + r]      = acc0[j];
      red[rr*64 + 32 + r] = acc1[j];
    }
  }
  __syncthreads();
  if (kw == 0){
    #pragma unroll
    for (int j=0; j<16; ++j){
      int rr = (j&3) + 8*(j>>2) + 4*hsub;
      float v0 = acc0[j] + red[rr*64 + r]      + bias[r];
      float v1 = acc1[j] + red[rr*64 + 32 + r] + bias[32 + r];
      G[(size_t)(row0 + rr)*HCOL + r]      = fmaxf(v0, 0.f);
      G[(size_t)(row0 + rr)*HCOL + 32 + r] = fmaxf(v1, 0.f);
    }
  }
}

// ---------------- projection: out[h][n] = sum_f in[n][f]*W[f][h], bf16 out ----------------
template<int F>
__global__ __launch_bounds__(128) void proj_T_kernel(
    const float* __restrict__ in,   // [N][F]
    const float* __restrict__ W,    // [F][64]
    __bf16* __restrict__ out)       // [64][N]
{
  constexpr int FP = F + 4;
  __shared__ float sWt[64*FP];      // W transposed [h][f], padded
  __shared__ short sOut[64*136];    // [h][128 nodes], padded

  int tid = threadIdx.x;
  for (int e = tid; e < 64*F; e += 128){
    int h = e / F, j = e - h*F;
    sWt[h*FP + j] = W[j*64 + h];
  }
  __syncthreads();

  const size_t n = (size_t)blockIdx.x*128 + tid;
  float rowv[F];
  #pragma unroll
  for (int j=0; j<F; j+=4){
    f32x4v v = *(const f32x4v*)(in + n*F + j);
    rowv[j]=v[0]; rowv[j+1]=v[1]; rowv[j+2]=v[2]; rowv[j+3]=v[3];
  }
  #pragma unroll
  for (int h=0; h<64; ++h){
    float s = 0.f;
    #pragma unroll
    for (int j=0; j<F; j+=4){
      f32x4v w = *(const f32x4v*)&sWt[h*FP + j];
      s += rowv[j]*w[0] + rowv[j+1]*w[1] + rowv[j+2]*w[2] + rowv[j+3]*w[3];
    }
    sOut[h*136 + tid] = __builtin_bit_cast(short, (__bf16)s);
  }
  __syncthreads();

  const size_t n0 = (size_t)blockIdx.x*128;
  #pragma unroll
  for (int pi=0; pi<8; ++pi){
    int p = pi*128 + tid;
    int h = p >> 4, cc = p & 15;
    i32x4 v = *(const i32x4*)&sOut[h*136 + cc*8];
    *(i32x4*)(out + (size_t)h*NNODE + n0 + cc*8) = v;
  }
}

// ---------------- tail MLP: out[n] = relu(g2[n]@Wd1+bd1)@Wd2 + bd2 ----------------
__global__ __launch_bounds__(256) void tail_kernel(
    const float* __restrict__ g2,   // [N][64]
    const float* __restrict__ Wd1,  // [64][32]
    const float* __restrict__ bd1,  // [32]
    const float* __restrict__ Wd2,  // [32][1]
    const float* __restrict__ bd2,  // [1]
    float* __restrict__ outp)       // [N]
{
  __shared__ float sW[64*32];
  __shared__ float sb1[32], sw2[32];
  int tid = threadIdx.x;
  for (int e=tid; e<2048; e+=256) sW[e] = Wd1[e];
  if (tid < 32){ sb1[tid] = bd1[tid]; sw2[tid] = Wd2[tid]; }
  __syncthreads();

  size_t n = (size_t)blockIdx.x*256 + tid;
  float rv[64];
  #pragma unroll
  for (int j=0;j<64;j+=4){
    f32x4v v = *(const f32x4v*)(g2 + n*64 + j);
    rv[j]=v[0]; rv[j+1]=v[1]; rv[j+2]=v[2]; rv[j+3]=v[3];
  }
  float o = 0.f;
  #pragma unroll
  for (int c=0;c<32;++c){
    float s = sb1[c];
    #pragma unroll
    for (int j=0;j<64;++j) s += rv[j]*sW[j*32 + c];
    o += fmaxf(s, 0.f) * sw2[c];
  }
  outp[n] = o + bd2[0];
}

extern "C" void kernel_launch(void* const* d_in, const int* in_sizes, int n_in,
                              void* d_out, int out_size, void* d_ws, size_t ws_size,
                              hipStream_t stream)
{
  const float* x   = (const float*)d_in[0];
  const float* a   = (const float*)d_in[1];
  const float* W1  = (const float*)d_in[2];
  const float* b1  = (const float*)d_in[3];
  const float* W2  = (const float*)d_in[4];
  const float* b2  = (const float*)d_in[5];
  const float* Wd1 = (const float*)d_in[6];
  const float* bd1 = (const float*)d_in[7];
  const float* Wd2 = (const float*)d_in[8];
  const float* bd2 = (const float*)d_in[9];
  float* outp = (float*)d_out;

  char* ws = (char*)d_ws;                       // needs 12 MB
  __bf16* Ht1 = (__bf16*)(ws);                  // [64][16384] bf16, 2 MB
  __bf16* Ht2 = (__bf16*)(ws + (2u<<20));       // 2 MB
  float*  g1  = (float*)(ws + (4u<<20));        // [16384][64] f32, 4 MB
  float*  g2  = (float*)(ws + (8u<<20));        // 4 MB

  proj_T_kernel<32><<<128, 128, 0, stream>>>(x,  W1, Ht1);
  gcn_layer_kernel <<<512, 128, 0, stream>>>(a, Ht1, b1, g1);
  proj_T_kernel<64><<<128, 128, 0, stream>>>(g1, W2, Ht2);
  gcn_layer_kernel <<<512, 128, 0, stream>>>(a, Ht2, b2, g2);
  tail_kernel      <<<64, 256, 0, stream>>>(g2, Wd1, bd1, Wd2, bd2, outp);
}

// Round 6
// 453.762 us; speedup vs baseline: 1.8526x; 1.1226x over previous
//
#include <hip/hip_runtime.h>
#include <hip/hip_bf16.h>

// GGCN: g1=relu(A@(x@W1)+b1); g2=relu(A@(g1@W2)+b2); out=relu(g2@Wd1+bd1)@Wd2+bd2
// N=16384, F=32, H=64, A dense f32 (1.07 GB, read twice -> HBM floor ~341us).
// R6: BM=64 blocks (4 waves, wave-private K-quarter, barrier-free main loop).
// Theory: R1/R5's 512 blocks each re-read the full 2MB Ht (1GB logical) while
// the A-stream thrashes L2 -> extra HBM traffic. 256 blocks halve Ht traffic.
// Wave count (1024) and per-wave MACs unchanged vs R5 -> clean A/B on Ht bytes.

typedef __bf16 bf16x8 __attribute__((ext_vector_type(8)));
typedef float  f32x16 __attribute__((ext_vector_type(16)));
typedef float  f32x4v __attribute__((ext_vector_type(4)));
typedef int    i32x4  __attribute__((ext_vector_type(4)));

#define NNODE 16384
#define KDIM  16384
#define HCOL  64

__device__ inline i32x4 pack8(f32x4v a, f32x4v b){
  bf16x8 t;
  t[0]=(__bf16)a[0]; t[1]=(__bf16)a[1]; t[2]=(__bf16)a[2]; t[3]=(__bf16)a[3];
  t[4]=(__bf16)b[0]; t[5]=(__bf16)b[1]; t[6]=(__bf16)b[2]; t[7]=(__bf16)b[3];
  return __builtin_bit_cast(i32x4, t);
}
#define BC(x) __builtin_bit_cast(bf16x8, x)

// ---------------- big kernel: G = relu(A @ Ht^T + bias) ----------------
// block = 256 thr (4 waves). BM=64 rows. wave kw owns K-quarter kw (wave-private
// LDS dbuf, no main-loop barriers). XOR swizzle on 16B chunks: c ^ (row&7).
__global__ __launch_bounds__(256, 1) void gcn_layer_kernel(
    const float* __restrict__ A,      // [16384][16384] f32
    const __bf16* __restrict__ Ht,    // [64][16384] bf16 (transposed H)
    const float* __restrict__ bias,   // [64]
    float* __restrict__ G)            // [16384][64] f32
{
  __shared__ i32x4 sA[4*2*512];   // (kw,buf) x 64 rows x 8 chunks = 64 KB
  __shared__ i32x4 sH[4*2*512];   // (kw,buf) x 64 rows x 8 chunks = 64 KB

  const int tid  = threadIdx.x;
  const int lane = tid & 63;
  const int kw   = tid >> 6;          // K-quarter 0..3
  const int row0 = blockIdx.x * 64;

  const int rA0  = lane >> 3;         // 0..7 staging row-in-group
  const int ccA  = lane & 7;          // staging logical 16B chunk (of 8 per 64k)
  const int swzA = ccA ^ rA0;         // row&7 == rA0 for all staged rows
  const int r    = lane & 31;
  const int hsub = lane >> 5;         // 0/1 k-subgroup within 16-k window
  const int xs   = r & 7;

  const size_t k0 = (size_t)kw * 4096;

  f32x4v ra[16]; i32x4 rh[8];

  const float* pA0 = A + (size_t)(row0 + rA0) * KDIM + k0 + (size_t)ccA*8;
  const i32x4* pH0 = (const i32x4*)Ht + (size_t)rA0 * (KDIM/8) + k0/8 + ccA;

  auto stage_load = [&](int t){
    const float* pA = pA0 + (size_t)t*64;
    #pragma unroll
    for (int pi=0; pi<8; ++pi){                    // rows rA0 + pi*8 (64 rows)
      const float* p = pA + (size_t)pi*8*KDIM;
      ra[2*pi]   = __builtin_nontemporal_load((const f32x4v*)p);   // A: stream, don't pollute L2
      ra[2*pi+1] = __builtin_nontemporal_load((const f32x4v*)(p+4));
    }
    const i32x4* pH = pH0 + (size_t)t*8;
    #pragma unroll
    for (int pi=0; pi<8; ++pi)
      rh[pi] = pH[(size_t)pi*8*(KDIM/8)];          // Ht: keep L2-cached
  };

  auto stage_write = [&](int buf){
    i32x4* dA = &sA[(kw*2+buf)*512];
    #pragma unroll
    for (int pi=0; pi<8; ++pi)
      dA[(rA0 + pi*8)*8 + swzA] = pack8(ra[2*pi], ra[2*pi+1]);
    i32x4* dH = &sH[(kw*2+buf)*512];
    #pragma unroll
    for (int pi=0; pi<8; ++pi)
      dH[(rA0 + pi*8)*8 + swzA] = rh[pi];
  };

  f32x16 acc00 = {}, acc01 = {}, acc10 = {}, acc11 = {};

  auto compute = [&](int buf){
    const i32x4* bA = &sA[(kw*2+buf)*512];
    const i32x4* bH = &sH[(kw*2+buf)*512];
    #pragma unroll
    for (int kk=0; kk<4; ++kk){
      int c = (kk*2 + hsub) ^ xs;                  // (r+32)&7 == r&7 -> same c
      bf16x8 a0 = BC(bA[r*8 + c]);
      bf16x8 a1 = BC(bA[(r+32)*8 + c]);
      bf16x8 b0 = BC(bH[r*8 + c]);
      bf16x8 b1 = BC(bH[(r+32)*8 + c]);
      acc00 = __builtin_amdgcn_mfma_f32_32x32x16_bf16(a0, b0, acc00, 0,0,0);
      acc01 = __builtin_amdgcn_mfma_f32_32x32x16_bf16(a0, b1, acc01, 0,0,0);
      acc10 = __builtin_amdgcn_mfma_f32_32x32x16_bf16(a1, b0, acc10, 0,0,0);
      acc11 = __builtin_amdgcn_mfma_f32_32x32x16_bf16(a1, b1, acc11, 0,0,0);
    }
  };

  // barrier-free per-wave pipeline over 64 tiles (k-quarter, 64 k each)
  stage_load(0);
  stage_write(0);
  stage_load(1);
  #pragma unroll 1
  for (int t=0; t<63; ++t){
    compute(t&1);
    stage_write((t+1)&1);
    if (t < 62) stage_load(t+2);
  }
  compute(1);                  // tile 63

  __syncthreads();             // red aliases kw0..2's sA regions

  // split-K=4 reduce: waves 1..3 dump partials, wave 0 combines
  float* red = (float*)sA;     // 3 x 64x64 f32 = 48 KB
  if (kw > 0){
    float* rd = red + (size_t)(kw-1)*4096;
    #pragma unroll
    for (int j=0; j<16; ++j){
      int rr = (j&3) + 8*(j>>2) + 4*hsub;          // C/D layout [verified R1..R5]
      rd[(rr   )*64 + r]      = acc00[j];
      rd[(rr   )*64 + 32 + r] = acc01[j];
      rd[(rr+32)*64 + r]      = acc10[j];
      rd[(rr+32)*64 + 32 + r] = acc11[j];
    }
  }
  __syncthreads();
  if (kw == 0){
    #pragma unroll
    for (int j=0; j<16; ++j){
      int rr = (j&3) + 8*(j>>2) + 4*hsub;
      float v00 = acc00[j] + red[(rr   )*64+r]    + red[4096+(rr   )*64+r]    + red[8192+(rr   )*64+r]    + bias[r];
      float v01 = acc01[j] + red[(rr   )*64+32+r] + red[4096+(rr   )*64+32+r] + red[8192+(rr   )*64+32+r] + bias[32+r];
      float v10 = acc10[j] + red[(rr+32)*64+r]    + red[4096+(rr+32)*64+r]    + red[8192+(rr+32)*64+r]    + bias[r];
      float v11 = acc11[j] + red[(rr+32)*64+32+r] + red[4096+(rr+32)*64+32+r] + red[8192+(rr+32)*64+32+r] + bias[32+r];
      G[(size_t)(row0 + rr     )*HCOL + r]      = fmaxf(v00, 0.f);
      G[(size_t)(row0 + rr     )*HCOL + 32 + r] = fmaxf(v01, 0.f);
      G[(size_t)(row0 + rr + 32)*HCOL + r]      = fmaxf(v10, 0.f);
      G[(size_t)(row0 + rr + 32)*HCOL + 32 + r] = fmaxf(v11, 0.f);
    }
  }
}

// ---------------- projection: out[h][n] = sum_f in[n][f]*W[f][h], bf16 out ----------------
template<int F>
__global__ __launch_bounds__(128) void proj_T_kernel(
    const float* __restrict__ in,   // [N][F]
    const float* __restrict__ W,    // [F][64]
    __bf16* __restrict__ out)       // [64][N]
{
  constexpr int FP = F + 4;
  __shared__ float sWt[64*FP];      // W transposed [h][f], padded
  __shared__ short sOut[64*136];    // [h][128 nodes], padded

  int tid = threadIdx.x;
  for (int e = tid; e < 64*F; e += 128){
    int h = e / F, j = e - h*F;
    sWt[h*FP + j] = W[j*64 + h];
  }
  __syncthreads();

  const size_t n = (size_t)blockIdx.x*128 + tid;
  float rowv[F];
  #pragma unroll
  for (int j=0; j<F; j+=4){
    f32x4v v = *(const f32x4v*)(in + n*F + j);
    rowv[j]=v[0]; rowv[j+1]=v[1]; rowv[j+2]=v[2]; rowv[j+3]=v[3];
  }
  #pragma unroll
  for (int h=0; h<64; ++h){
    float s = 0.f;
    #pragma unroll
    for (int j=0; j<F; j+=4){
      f32x4v w = *(const f32x4v*)&sWt[h*FP + j];
      s += rowv[j]*w[0] + rowv[j+1]*w[1] + rowv[j+2]*w[2] + rowv[j+3]*w[3];
    }
    sOut[h*136 + tid] = __builtin_bit_cast(short, (__bf16)s);
  }
  __syncthreads();

  const size_t n0 = (size_t)blockIdx.x*128;
  #pragma unroll
  for (int pi=0; pi<8; ++pi){
    int p = pi*128 + tid;
    int h = p >> 4, cc = p & 15;
    i32x4 v = *(const i32x4*)&sOut[h*136 + cc*8];
    *(i32x4*)(out + (size_t)h*NNODE + n0 + cc*8) = v;
  }
}

// ---------------- tail MLP: out[n] = relu(g2[n]@Wd1+bd1)@Wd2 + bd2 ----------------
__global__ __launch_bounds__(256) void tail_kernel(
    const float* __restrict__ g2,   // [N][64]
    const float* __restrict__ Wd1,  // [64][32]
    const float* __restrict__ bd1,  // [32]
    const float* __restrict__ Wd2,  // [32][1]
    const float* __restrict__ bd2,  // [1]
    float* __restrict__ outp)       // [N]
{
  __shared__ float sW[64*32];
  __shared__ float sb1[32], sw2[32];
  int tid = threadIdx.x;
  for (int e=tid; e<2048; e+=256) sW[e] = Wd1[e];
  if (tid < 32){ sb1[tid] = bd1[tid]; sw2[tid] = Wd2[tid]; }
  __syncthreads();

  size_t n = (size_t)blockIdx.x*256 + tid;
  float rv[64];
  #pragma unroll
  for (int j=0;j<64;j+=4){
    f32x4v v = *(const f32x4v*)(g2 + n*64 + j);
    rv[j]=v[0]; rv[j+1]=v[1]; rv[j+2]=v[2]; rv[j+3]=v[3];
  }
  float o = 0.f;
  #pragma unroll
  for (int c=0;c<32;++c){
    float s = sb1[c];
    #pragma unroll
    for (int j=0;j<64;++j) s += rv[j]*sW[j*32 + c];
    o += fmaxf(s, 0.f) * sw2[c];
  }
  outp[n] = o + bd2[0];
}

extern "C" void kernel_launch(void* const* d_in, const int* in_sizes, int n_in,
                              void* d_out, int out_size, void* d_ws, size_t ws_size,
                              hipStream_t stream)
{
  const float* x   = (const float*)d_in[0];
  const float* a   = (const float*)d_in[1];
  const float* W1  = (const float*)d_in[2];
  const float* b1  = (const float*)d_in[3];
  const float* W2  = (const float*)d_in[4];
  const float* b2  = (const float*)d_in[5];
  const float* Wd1 = (const float*)d_in[6];
  const float* bd1 = (const float*)d_in[7];
  const float* Wd2 = (const float*)d_in[8];
  const float* bd2 = (const float*)d_in[9];
  float* outp = (float*)d_out;

  char* ws = (char*)d_ws;                       // needs 12 MB
  __bf16* Ht1 = (__bf16*)(ws);                  // [64][16384] bf16, 2 MB
  __bf16* Ht2 = (__bf16*)(ws + (2u<<20));       // 2 MB
  float*  g1  = (float*)(ws + (4u<<20));        // [16384][64] f32, 4 MB
  float*  g2  = (float*)(ws + (8u<<20));        // 4 MB

  proj_T_kernel<32><<<128, 128, 0, stream>>>(x,  W1, Ht1);
  gcn_layer_kernel <<<256, 256, 0, stream>>>(a, Ht1, b1, g1);
  proj_T_kernel<64><<<128, 128, 0, stream>>>(g1, W2, Ht2);
  gcn_layer_kernel <<<256, 256, 0, stream>>>(a, Ht2, b2, g2);
  tail_kernel      <<<64, 256, 0, stream>>>(g2, Wd1, bd1, Wd2, bd2, outp);
}